// Round 3
// baseline (70.443 us; speedup 1.0000x reference)
//
#include <hip/hip_runtime.h>
#include <math.h>

#define LQ 256
#define MEML 256
#define LK 512
#define BB 4
#define NH 8
#define DH 16
#define DM 128

constexpr float INV2PI = 0.15915494309189535f;

// ---------------------------------------------------------------------------
// Projection + sincos tables, pre-scaled by paramR[h]/(2*pi):
//   q-side  (row-major): qv/qsn/qcs[row=i*4+b][o=h*16+d]
//   k-side  (transposed): kv/ksn/kcs[d4][j][bh*4+(d&3)]  (1KB/wave coalesced)
// 4 rows per block, 128 threads (one per output column o).
// ---------------------------------------------------------------------------
__global__ __launch_bounds__(128) void proj_kernel(
    const float* __restrict__ hh, const float* __restrict__ mems,
    const float* __restrict__ Wq, const float* __restrict__ Wk,
    const float* __restrict__ paramR,
    float* __restrict__ qv, float* __restrict__ qsn, float* __restrict__ qcs,
    float* __restrict__ kv, float* __restrict__ ksn, float* __restrict__ kcs)
{
    __shared__ float x[4 * 128];
    const int blk = blockIdx.x;
    const int t = threadIdx.x;
    const bool isQ = (blk < 256);                 // 256 q-blocks, 512 k-blocks
    const int row0 = isQ ? blk * 4 : (blk - 256) * 4;
    const float* __restrict__ W = isQ ? Wq : Wk;

    for (int r = 0; r < 4; ++r) {
        const int row = row0 + r;
        const float* src;
        if (isQ) src = hh + row * DM;
        else     src = (row < MEML * BB) ? (mems + row * DM)
                                         : (hh + (row - MEML * BB) * DM);
        x[r * 128 + t] = src[t];
    }
    __syncthreads();

    float acc[4] = {0, 0, 0, 0};
    const float* wrow = W + t * DM;
    for (int k = 0; k < DM; k += 4) {
        const float4 w = *(const float4*)(wrow + k);
        #pragma unroll
        for (int r = 0; r < 4; ++r) {
            acc[r] += x[r * 128 + k + 0] * w.x + x[r * 128 + k + 1] * w.y
                    + x[r * 128 + k + 2] * w.z + x[r * 128 + k + 3] * w.w;
        }
    }
    const int h = t >> 4, d = t & 15;
    const float rs = paramR[h] * INV2PI;
    if (isQ) {
        #pragma unroll
        for (int r = 0; r < 4; ++r) {
            const float v = acc[r] * rs;
            const int idx = (row0 + r) * 128 + t;
            qv[idx]  = v;
            qsn[idx] = __builtin_amdgcn_sinf(v);  // sin(2pi*v)
            qcs[idx] = __builtin_amdgcn_cosf(v);  // cos(2pi*v)
        }
    } else {
        #pragma unroll
        for (int r = 0; r < 4; ++r) {
            const float v = acc[r] * rs;
            const int row = row0 + r;
            const int j = row >> 2, b = row & 3;
            const int idx = ((d >> 2) * LK + j) * 128 + (b * 8 + h) * 4 + (d & 3);
            kv[idx]  = v;
            ksn[idx] = __builtin_amdgcn_sinf(v);
            kcs[idx] = __builtin_amdgcn_cosf(v);
        }
    }
}

// ---------------------------------------------------------------------------
// Score, zero transcendentals in the hot loop:
//   sin(2pi(q-k)) = sq*ck - cq*sk ;  factor = num/delta * (1/2pi)
//   out = |prodN/prodD| * (2pi)^-16, guard |delta|<=EPS -> factor := 1
// Thread: bh=t&31, js=t>>5, one i per block-x. Block: 1 i x 64 j.
// ---------------------------------------------------------------------------
__global__ __launch_bounds__(256) void score_kernel(
    const float* __restrict__ qv, const float* __restrict__ qsn,
    const float* __restrict__ qcs,
    const float* __restrict__ kv, const float* __restrict__ ksn,
    const float* __restrict__ kcs,
    float* __restrict__ out)
{
    const int t = threadIdx.x;
    const int bh = t & 31;
    const int js = t >> 5;                        // 0..7
    const int i = blockIdx.x;                     // 256
    const int jbase = blockIdx.y * 64;            // 8

    constexpr float i2 = INV2PI * INV2PI;
    constexpr float i4 = i2 * i2;
    constexpr float i8 = i4 * i4;
    constexpr float C16 = i8 * i8;                // (2pi)^-16
    constexpr float EPS = 4.0e-4f;                // revolutions

    float q[16], sq[16], cq[16];
    {
        const int qoff = (i * 32 + bh) * 16;
        #pragma unroll
        for (int d = 0; d < 16; d += 4) {
            const float4 a = *(const float4*)(qv  + qoff + d);
            const float4 b = *(const float4*)(qsn + qoff + d);
            const float4 c = *(const float4*)(qcs + qoff + d);
            q[d] = a.x;  q[d+1] = a.y;  q[d+2] = a.z;  q[d+3] = a.w;
            sq[d] = b.x; sq[d+1] = b.y; sq[d+2] = b.z; sq[d+3] = b.w;
            cq[d] = c.x; cq[d+1] = c.y; cq[d+2] = c.z; cq[d+3] = c.w;
        }
    }

    float ka[2][16], ska[2][16], cka[2][16];
    {
        const int j0 = jbase + js;
        #pragma unroll
        for (int d4 = 0; d4 < 4; ++d4) {
            const int off = (d4 * LK + j0) * 128 + bh * 4;
            const float4 a = *(const float4*)(kv  + off);
            const float4 b = *(const float4*)(ksn + off);
            const float4 c = *(const float4*)(kcs + off);
            ka[0][d4*4] = a.x;  ka[0][d4*4+1] = a.y;  ka[0][d4*4+2] = a.z;  ka[0][d4*4+3] = a.w;
            ska[0][d4*4] = b.x; ska[0][d4*4+1] = b.y; ska[0][d4*4+2] = b.z; ska[0][d4*4+3] = b.w;
            cka[0][d4*4] = c.x; cka[0][d4*4+1] = c.y; cka[0][d4*4+2] = c.z; cka[0][d4*4+3] = c.w;
        }
    }

    #pragma unroll
    for (int m = 0; m < 8; ++m) {
        const int cur = m & 1, nxt = cur ^ 1;
        if (m < 7) {
            const int jn = jbase + (m + 1) * 8 + js;
            #pragma unroll
            for (int d4 = 0; d4 < 4; ++d4) {
                const int off = (d4 * LK + jn) * 128 + bh * 4;
                const float4 a = *(const float4*)(kv  + off);
                const float4 b = *(const float4*)(ksn + off);
                const float4 c = *(const float4*)(kcs + off);
                ka[nxt][d4*4] = a.x;  ka[nxt][d4*4+1] = a.y;  ka[nxt][d4*4+2] = a.z;  ka[nxt][d4*4+3] = a.w;
                ska[nxt][d4*4] = b.x; ska[nxt][d4*4+1] = b.y; ska[nxt][d4*4+2] = b.z; ska[nxt][d4*4+3] = b.w;
                cka[nxt][d4*4] = c.x; cka[nxt][d4*4+1] = c.y; cka[nxt][d4*4+2] = c.z; cka[nxt][d4*4+3] = c.w;
            }
        }
        const int j = jbase + m * 8 + js;
        float pn0 = 1.f, pd0 = 1.f, pn1 = 1.f, pd1 = 1.f;
        #pragma unroll
        for (int d = 0; d < 16; ++d) {
            const float dl = q[d] - ka[cur][d];
            const float num = sq[d] * cka[cur][d] - cq[d] * ska[cur][d];
            const bool g = __builtin_fabsf(dl) > EPS;
            const float nn = g ? num : 1.0f;
            const float dd = g ? dl : INV2PI;
            if (d < 8) { pn0 *= nn; pd0 *= dd; }
            else       { pn1 *= nn; pd1 *= dd; }
        }
        const float r0 = pn0 * __builtin_amdgcn_rcpf(pd0);
        const float r1 = pn1 * __builtin_amdgcn_rcpf(pd1);
        out[(i * LK + j) * 32 + bh] = __builtin_fabsf(r0 * r1) * C16;
    }
}

extern "C" void kernel_launch(void* const* d_in, const int* in_sizes, int n_in,
                              void* d_out, int out_size, void* d_ws, size_t ws_size,
                              hipStream_t stream) {
    const float* hh     = (const float*)d_in[0];
    const float* mems   = (const float*)d_in[1];
    const float* Wq     = (const float*)d_in[2];
    const float* Wk     = (const float*)d_in[3];
    const float* paramR = (const float*)d_in[4];
    float* out = (float*)d_out;

    float* qv  = (float*)d_ws;                // 131072 floats each (q tables)
    float* qsn = qv  + LQ * BB * DM;
    float* qcs = qsn + LQ * BB * DM;
    float* kv  = qcs + LQ * BB * DM;          // 262144 floats each (k tables)
    float* ksn = kv  + LK * BB * DM;
    float* kcs = ksn + LK * BB * DM;

    proj_kernel<<<768, 128, 0, stream>>>(hh, mems, Wq, Wk, paramR,
                                         qv, qsn, qcs, kv, ksn, kcs);
    score_kernel<<<dim3(256, 8), 256, 0, stream>>>(qv, qsn, qcs, kv, ksn, kcs, out);
}

// Round 4
// 46.804 us; speedup vs baseline: 1.5051x; 1.5051x over previous
//
#include <hip/hip_runtime.h>
#include <math.h>

#define LQ 256
#define MEML 256
#define LK 512
#define BB 4
#define NH 8
#define DH 16
#define DM 128

constexpr float INV2PI = 0.15915494309189535f;

// ---------------------------------------------------------------------------
// Projection + sincos tables, pre-scaled by paramR[h]/(2*pi). ALL row-major:
//   q-side: qv/qsn/qcs[(i*4+b)*128 + h*16+d]   (1024 rows)
//   k-side: krv/krs/krc[(j*4+b)*128 + h*16+d]  (2048 rows; krow = scratch in d_out)
// 4 rows per block, 128 threads (one per output column o).
// ---------------------------------------------------------------------------
__global__ __launch_bounds__(128) void proj_kernel(
    const float* __restrict__ hh, const float* __restrict__ mems,
    const float* __restrict__ Wq, const float* __restrict__ Wk,
    const float* __restrict__ paramR,
    float* __restrict__ qv, float* __restrict__ qsn, float* __restrict__ qcs,
    float* __restrict__ krv, float* __restrict__ krs, float* __restrict__ krc)
{
    __shared__ float x[4 * 128];
    const int blk = blockIdx.x;
    const int t = threadIdx.x;
    const bool isQ = (blk < 256);                 // 256 q-blocks, 512 k-blocks
    const int row0 = isQ ? blk * 4 : (blk - 256) * 4;
    const float* __restrict__ W = isQ ? Wq : Wk;

    for (int r = 0; r < 4; ++r) {
        const int row = row0 + r;
        const float* src;
        if (isQ) src = hh + row * DM;
        else     src = (row < MEML * BB) ? (mems + row * DM)
                                         : (hh + (row - MEML * BB) * DM);
        x[r * 128 + t] = src[t];
    }
    __syncthreads();

    float acc[4] = {0, 0, 0, 0};
    const float* wrow = W + t * DM;
    for (int k = 0; k < DM; k += 4) {
        const float4 w = *(const float4*)(wrow + k);
        #pragma unroll
        for (int r = 0; r < 4; ++r) {
            acc[r] += x[r * 128 + k + 0] * w.x + x[r * 128 + k + 1] * w.y
                    + x[r * 128 + k + 2] * w.z + x[r * 128 + k + 3] * w.w;
        }
    }
    const float rs = paramR[t >> 4] * INV2PI;
    float* __restrict__ dv = isQ ? qv  : krv;
    float* __restrict__ ds = isQ ? qsn : krs;
    float* __restrict__ dc = isQ ? qcs : krc;
    #pragma unroll
    for (int r = 0; r < 4; ++r) {
        const float v = acc[r] * rs;
        const int idx = (row0 + r) * 128 + t;
        dv[idx] = v;
        ds[idx] = __builtin_amdgcn_sinf(v);       // sin(2pi*v)
        dc[idx] = __builtin_amdgcn_cosf(v);       // cos(2pi*v)
    }
}

// ---------------------------------------------------------------------------
// Transpose k tables: kT*[(bh*16+d)*512 + j] = kr*[(j*4+b)*128 + h*16+d]
// where bh = b*8+h  (so row index = b*128 + o, o = h*16+d).
// Block: 64 j x 128 o for one b; LDS tile with +1 pad.
// ---------------------------------------------------------------------------
__global__ __launch_bounds__(256) void ktrans_kernel(
    const float* __restrict__ krv, const float* __restrict__ krs,
    const float* __restrict__ krc,
    float* __restrict__ kTv, float* __restrict__ kTs, float* __restrict__ kTc)
{
    __shared__ float tile[64 * 129];
    const int t = threadIdx.x;
    const int j0 = blockIdx.x * 64;               // 8
    const int b  = blockIdx.y;                    // 4
    const float* srcs[3] = {krv, krs, krc};
    float*       dsts[3] = {kTv, kTs, kTc};
    #pragma unroll 3
    for (int a = 0; a < 3; ++a) {
        const float* __restrict__ src = srcs[a];
        float* __restrict__ dst = dsts[a];
        #pragma unroll
        for (int rep = 0; rep < 32; ++rep) {
            const int idx = rep * 256 + t;
            const int jL = idx >> 7, o = idx & 127;
            tile[jL * 129 + o] = src[((j0 + jL) * 4 + b) * 128 + o];
        }
        __syncthreads();
        #pragma unroll
        for (int rep = 0; rep < 32; ++rep) {
            const int idx = rep * 256 + t;
            const int o = idx >> 6, jL = idx & 63;
            dst[(b * 128 + o) * 512 + j0 + jL] = tile[jL * 129 + o];
        }
        __syncthreads();
    }
}

// ---------------------------------------------------------------------------
// Score. wave w (0..15) -> bh = bhh*16+w (WAVE-UNIFORM -> q scalar loads);
// lane -> j. k-triple (48 VGPR) loaded once per block, reused over 16 i's.
// Per i: compute 1 output/thread, transpose 64x16 tile through LDS, store
// full 64B lines coalesced.
// ---------------------------------------------------------------------------
__global__ __launch_bounds__(1024) void score_kernel(
    const float* __restrict__ qv, const float* __restrict__ qsn,
    const float* __restrict__ qcs,
    const float* __restrict__ kTv, const float* __restrict__ kTs,
    const float* __restrict__ kTc,
    float* __restrict__ out)
{
    __shared__ float trsp[64 * 17];
    const int t = threadIdx.x;
    const int lane = t & 63;
    const int w = __builtin_amdgcn_readfirstlane(t >> 6);   // 0..15, uniform
    const int bhh = blockIdx.z;                             // 0..1
    const int bh = bhh * 16 + w;
    const int j = blockIdx.y * 64 + lane;                   // 0..511
    const int i0 = blockIdx.x * 16;

    constexpr float i2 = INV2PI * INV2PI;
    constexpr float i4 = i2 * i2;
    constexpr float i8 = i4 * i4;
    constexpr float C16 = i8 * i8;                // (2pi)^-16
    constexpr float EPS = 4.0e-4f;                // revolutions

    float kd[16], ksn[16], kcs[16];
    #pragma unroll
    for (int d = 0; d < 16; ++d) {
        const int off = (bh * 16 + d) * LK + j;   // lanes consecutive: coalesced
        kd[d]  = kTv[off];
        ksn[d] = kTs[off];
        kcs[d] = kTc[off];
    }

    const int jL = t >> 4, bl = t & 15;

    for (int ii = 0; ii < 16; ++ii) {
        const int i = i0 + ii;
        const int qbase = (i * 32 + bh) * 16;     // uniform per wave
        float rhalf[2];
        #pragma unroll
        for (int hf = 0; hf < 2; ++hf) {
            float qd[8], qs_[8], qc_[8];
            #pragma unroll
            for (int dq = 0; dq < 8; dq += 4) {
                const float4 a = *(const float4*)(qv  + qbase + hf * 8 + dq);
                const float4 s = *(const float4*)(qsn + qbase + hf * 8 + dq);
                const float4 c = *(const float4*)(qcs + qbase + hf * 8 + dq);
                qd[dq]  = a.x; qd[dq+1]  = a.y; qd[dq+2]  = a.z; qd[dq+3]  = a.w;
                qs_[dq] = s.x; qs_[dq+1] = s.y; qs_[dq+2] = s.z; qs_[dq+3] = s.w;
                qc_[dq] = c.x; qc_[dq+1] = c.y; qc_[dq+2] = c.z; qc_[dq+3] = c.w;
            }
            float pn = 1.f, pd = 1.f;
            #pragma unroll
            for (int d = 0; d < 8; ++d) {
                const int dk = hf * 8 + d;
                const float dl  = qd[d] - kd[dk];
                const float num = qs_[d] * kcs[dk] - qc_[d] * ksn[dk];
                const bool  g   = __builtin_fabsf(dl) > EPS;
                pn *= g ? num : 1.0f;
                pd *= g ? dl : INV2PI;
            }
            rhalf[hf] = pn * __builtin_amdgcn_rcpf(pd);
        }
        const float r = __builtin_fabsf(rhalf[0] * rhalf[1]) * C16;

        trsp[lane * 17 + w] = r;
        __syncthreads();
        out[(i * LK + blockIdx.y * 64 + jL) * 32 + bhh * 16 + bl] = trsp[jL * 17 + bl];
        __syncthreads();
    }
}

extern "C" void kernel_launch(void* const* d_in, const int* in_sizes, int n_in,
                              void* d_out, int out_size, void* d_ws, size_t ws_size,
                              hipStream_t stream) {
    const float* hh     = (const float*)d_in[0];
    const float* mems   = (const float*)d_in[1];
    const float* Wq     = (const float*)d_in[2];
    const float* Wk     = (const float*)d_in[3];
    const float* paramR = (const float*)d_in[4];
    float* out = (float*)d_out;

    // workspace: q tables (3 x 131072) + transposed k tables (3 x 262144)
    float* qv  = (float*)d_ws;
    float* qsn = qv  + LQ * BB * DM;
    float* qcs = qsn + LQ * BB * DM;
    float* kTv = qcs + LQ * BB * DM;
    float* kTs = kTv + LK * BB * DM;
    float* kTc = kTs + LK * BB * DM;

    // k row-major scratch lives in d_out (written before read, then fully
    // overwritten by score_kernel -> deterministic).
    float* krv = out;                              // 262144 floats
    float* krs = krv + LK * BB * DM;
    float* krc = krs + LK * BB * DM;

    proj_kernel<<<768, 128, 0, stream>>>(hh, mems, Wq, Wk, paramR,
                                         qv, qsn, qcs, krv, krs, krc);
    ktrans_kernel<<<dim3(8, 4), 256, 0, stream>>>(krv, krs, krc, kTv, kTs, kTc);
    score_kernel<<<dim3(16, 8, 2), 1024, 0, stream>>>(qv, qsn, qcs,
                                                      kTv, kTs, kTc, out);
}

// Round 6
// 46.377 us; speedup vs baseline: 1.5189x; 1.0092x over previous
//
#include <hip/hip_runtime.h>
#include <math.h>

#define LQ 256
#define MEML 256
#define LK 512
#define BB 4
#define NH 8
#define DH 16
#define DM 128

constexpr float INV2PI = 0.15915494309189535f;

// ---------------------------------------------------------------------------
// Projection + sincos tables, pre-scaled by paramR[h]/(2*pi):
//   q-side packed rows: qP[(i*32+bh)*48 + {d, 16+d, 32+d}] = {v, sin, cos}
//     (8192 rows x 48 floats)
//   k-side transposed:  kT*[(bh*16+d)*512 + j]   (coalesced along j)
// 4 input rows per block (one i or j), 128 threads (one per output column o).
// ---------------------------------------------------------------------------
__global__ __launch_bounds__(128) void proj_kernel(
    const float* __restrict__ hh, const float* __restrict__ mems,
    const float* __restrict__ Wq, const float* __restrict__ Wk,
    const float* __restrict__ paramR,
    float* __restrict__ qP,
    float* __restrict__ kTv, float* __restrict__ kTs, float* __restrict__ kTc)
{
    __shared__ float x[4 * 128];
    const int blk = blockIdx.x;
    const int t = threadIdx.x;
    const bool isQ = (blk < 256);                 // 256 q-blocks, 512 k-blocks
    const int row0 = isQ ? blk * 4 : (blk - 256) * 4;
    const float* __restrict__ W = isQ ? Wq : Wk;

    for (int r = 0; r < 4; ++r) {
        const int row = row0 + r;
        const float* src = isQ ? (hh + row * DM)
                               : ((row < MEML * BB) ? (mems + row * DM)
                                                    : (hh + (row - MEML * BB) * DM));
        x[r * 128 + t] = src[t];
    }
    __syncthreads();

    float acc[4] = {0, 0, 0, 0};
    const float* wrow = W + t * DM;
    for (int k = 0; k < DM; k += 4) {
        const float4 w = *(const float4*)(wrow + k);
        #pragma unroll
        for (int r = 0; r < 4; ++r) {
            acc[r] += x[r * 128 + k + 0] * w.x + x[r * 128 + k + 1] * w.y
                    + x[r * 128 + k + 2] * w.z + x[r * 128 + k + 3] * w.w;
        }
    }
    const int h = t >> 4, d = t & 15;
    const float rs = paramR[h] * INV2PI;
    #pragma unroll
    for (int r = 0; r < 4; ++r) {
        const float v = acc[r] * rs;
        const float sn = __builtin_amdgcn_sinf(v);    // sin(2pi*v)
        const float cs = __builtin_amdgcn_cosf(v);    // cos(2pi*v)
        const int row = row0 + r;
        const int b = row & 3;
        if (isQ) {
            const int i = row >> 2;
            float* qp = qP + (i * 32 + b * 8 + h) * 48;
            qp[d] = v; qp[16 + d] = sn; qp[32 + d] = cs;
        } else {
            const int j = row >> 2;
            const int idx = ((b * 8 + h) * 16 + d) * LK + j;
            kTv[idx] = v; kTs[idx] = sn; kTc[idx] = cs;
        }
    }
}

// ---------------------------------------------------------------------------
// Score. wave w (0..7) -> bh = z*8+w (uniform -> q via scalar loads);
// lane -> j. k-triple in 48 VGPRs, loaded once coalesced, reused over 16 i.
// NO barriers in the i-loop: 16 results held in VGPRs, one endgame LDS
// transpose (2 barriers total) then coalesced 32B-segment stores.
// ---------------------------------------------------------------------------
__global__ __launch_bounds__(512) void score_kernel(
    const float* __restrict__ qP,
    const float* __restrict__ kTv, const float* __restrict__ kTs,
    const float* __restrict__ kTc,
    float* __restrict__ out)
{
    __shared__ float tile[16 * 8 * 65];
    const int t = threadIdx.x;
    const int lane = t & 63;
    const int w = __builtin_amdgcn_readfirstlane(t >> 6);   // 0..7, uniform
    const int b = blockIdx.z;                               // 0..3
    const int bh = b * 8 + w;
    const int j = blockIdx.y * 64 + lane;
    const int i0 = blockIdx.x * 16;

    constexpr float i2 = INV2PI * INV2PI;
    constexpr float i4 = i2 * i2;
    constexpr float i8 = i4 * i4;
    constexpr float C16 = i8 * i8;                // (2pi)^-16
    constexpr float EPS = 4.0e-4f;                // revolutions

    float kd[16], ks[16], kc[16];
    #pragma unroll
    for (int d = 0; d < 16; ++d) {
        const int off = (bh * 16 + d) * LK + j;   // lanes consecutive: coalesced
        kd[d] = kTv[off];
        ks[d] = kTs[off];
        kc[d] = kTc[off];
    }

    float r[16];
    #pragma unroll
    for (int ii = 0; ii < 16; ++ii) {
        const int qrow = __builtin_amdgcn_readfirstlane(((i0 + ii) * 32 + bh) * 48);
        const float* __restrict__ qp = qP + qrow;
        float pn0 = 1.f, pd0 = 1.f, pn1 = 1.f, pd1 = 1.f;
        #pragma unroll
        for (int d = 0; d < 16; ++d) {
            const float dl  = qp[d] - kd[d];
            const float num = qp[16 + d] * kc[d] - qp[32 + d] * ks[d];
            const bool  g   = __builtin_fabsf(dl) > EPS;
            const float nn = g ? num : 1.0f;
            const float dd = g ? dl : INV2PI;
            if (d < 8) { pn0 *= nn; pd0 *= dd; }
            else       { pn1 *= nn; pd1 *= dd; }
        }
        r[ii] = __builtin_fabsf(pn0 * __builtin_amdgcn_rcpf(pd0)
                              * pn1 * __builtin_amdgcn_rcpf(pd1)) * C16;
    }

    #pragma unroll
    for (int ii = 0; ii < 16; ++ii)
        tile[(ii * 8 + w) * 65 + lane] = r[ii];
    __syncthreads();

    const int j0 = blockIdx.y * 64;
    #pragma unroll
    for (int rep = 0; rep < 16; ++rep) {
        const int idx = rep * 512 + t;
        const int bl = idx & 7;
        const int jL = (idx >> 3) & 63;
        const int ii = idx >> 9;
        out[((i0 + ii) * LK + j0 + jL) * 32 + b * 8 + bl] =
            tile[(ii * 8 + bl) * 65 + jL];
    }
}

extern "C" void kernel_launch(void* const* d_in, const int* in_sizes, int n_in,
                              void* d_out, int out_size, void* d_ws, size_t ws_size,
                              hipStream_t stream) {
    const float* hh     = (const float*)d_in[0];
    const float* mems   = (const float*)d_in[1];
    const float* Wq     = (const float*)d_in[2];
    const float* Wk     = (const float*)d_in[3];
    const float* paramR = (const float*)d_in[4];
    float* out = (float*)d_out;

    // qP: (LQ*BB*NH) = 8192 rows x 48 floats = 393216 floats  (FIX: was 49152)
    float* qP  = (float*)d_ws;
    float* kTv = qP  + LQ * BB * NH * 48;      // 262144 floats each
    float* kTs = kTv + LK * BB * DM;
    float* kTc = kTs + LK * BB * DM;

    proj_kernel<<<768, 128, 0, stream>>>(hh, mems, Wq, Wk, paramR,
                                         qP, kTv, kTs, kTc);
    score_kernel<<<dim3(16, 8, 4), 512, 0, stream>>>(qP, kTv, kTs, kTc, out);
}